// Round 14
// baseline (190.193 us; speedup 1.0000x reference)
//
#include <hip/hip_runtime.h>

#define NB    4096
#define TSTEP 256
#define DTC   0.01f

typedef _Float16 h8 __attribute__((ext_vector_type(8)));
typedef float    f4 __attribute__((ext_vector_type(4)));

// tanh(a) = (E-1)/(E+1), E=exp(2a); upper clamp only (exp2(-inf)->0 -> -1 cleanly)
__device__ __forceinline__ float fast_tanh(float a) {
    float t = fminf(a * 2.885390082f, 126.0f);
    float E = __builtin_amdgcn_exp2f(t);
    return (E - 1.0f) * __builtin_amdgcn_rcpf(E + 1.0f);
}
// exp(m) for |m| <= ~0.06: 3-term Taylor, rel err < 4e-7 (validated r13, absmax 36)
__device__ __forceinline__ float texp(float m) {
    return fmaf(m, fmaf(m, fmaf(m, 1.0f/6.0f, 0.5f), 1.0f), 1.0f);
}
// stacked block-diagonal layer-2 weight in TRUE coordinates
__device__ __forceinline__ float W2v(const float* Wc2, const float* Wr2, int C, int U) {
    if (C < 48) return (U < 48) ? Wc2[C*48 + U] : 0.0f;
    return (U >= 48) ? Wr2[(C-48)*16 + (U-48)] : 0.0f;
}

// Zero-exchange layout (per wave, 16 elems; lane = (e=lane&15, g=lane>>4)):
//  y true-feats at lane:   {12g..12g+11} (6 rot pairs) + {48+4g..+3} (4 r-modes)
//  L1 k-label   υ:  k=8g+i -> 12g+i ; k=32+8g+i -> i<4 ? 12g+8+i : 48+4g+(i-4)
//  u slot-label σ1: slot 16t+m -> 16*(m>>2)+4t+(m&3)   (lane's u-set = {16g..16g+15})
//  L2 k-label   τ:  k=8g+i -> 16g+i ; k=32+8g+i -> 16g+8+i   (== σ1 sets, no exchange)
//  c slot-label σ2: t<3: 12*(m>>2)+4t+(m&3) ; t=3: 48+4*(m>>2)+(m&3)
//  => rotation coeffs colocate with y pairs; r-modes = tile 3 (uniform, no branch)
__global__ void __launch_bounds__(64) __attribute__((amdgpu_waves_per_eu(1, 1)))
koopman_kernel(const float* __restrict__ x,
               const float* __restrict__ Wc1, const float* __restrict__ bc1,
               const float* __restrict__ Wc2, const float* __restrict__ bc2,
               const float* __restrict__ Wr1, const float* __restrict__ br1,
               const float* __restrict__ Wr2, const float* __restrict__ br2,
               float* __restrict__ out)
{
    const int lane = threadIdx.x & 63;
    const int e    = lane & 15;
    const int g    = lane >> 4;
    const int blk  = blockIdx.x;

    // ---- persistent A fragments with the double permutation baked in ----
    h8 a1lo[4], a1hi[4], a2lo[4], a2hi[4];
    #pragma unroll
    for (int t = 0; t < 4; ++t) {
        const int F1 = 16*(e>>2) + 4*t + (e&3);            // σ1 row
        const float* w1row = (F1 < 48) ? (Wc1 + F1*64) : (Wr1 + (F1-48)*64);
        #pragma unroll
        for (int i = 0; i < 8; ++i) a1lo[t][i] = (_Float16)w1row[12*g + i];
        #pragma unroll
        for (int i = 0; i < 8; ++i) {
            const int col = (i < 4) ? (12*g + 8 + i) : (48 + 4*g + (i-4));
            a1hi[t][i] = (_Float16)w1row[col];
        }
        const int C2 = (t < 3) ? (12*(e>>2) + 4*t + (e&3)) // σ2 row
                               : (48 + 4*(e>>2) + (e&3));
        #pragma unroll
        for (int i = 0; i < 8; ++i) a2lo[t][i] = (_Float16)W2v(Wc2, Wr2, C2, 16*g + i);
        #pragma unroll
        for (int i = 0; i < 8; ++i) a2hi[t][i] = (_Float16)W2v(Wc2, Wr2, C2, 16*g + 8 + i);
    }
    // biases in C/D layout (row 4g+r of tile t)
    f4 b1f[4], b2f[4];
    #pragma unroll
    for (int t = 0; t < 4; ++t) {
        #pragma unroll
        for (int r = 0; r < 4; ++r) {
            const int F = 16*g + 4*t + r;
            b1f[t][r] = (F < 48) ? bc1[F] : br1[F-48];
            const int C = (t < 3) ? (12*g + 4*t + r) : (48 + 4*g + r);
            b2f[t][r] = (C < 48) ? bc2[C] : br2[C-48];
        }
    }

    // ---- y state (f32) in B-fragment order ----
    const float* xp = x + (size_t)(blk*16 + e) * 64;
    float yv0[8], yv1[8];
    #pragma unroll
    for (int i = 0; i < 8; ++i) yv0[i] = xp[12*g + i];
    #pragma unroll
    for (int i = 0; i < 4; ++i) yv1[i] = xp[12*g + 8 + i];
    #pragma unroll
    for (int i = 0; i < 4; ++i) yv1[4+i] = xp[48 + 4*g + i];

    float* gp = out + (size_t)(blk*16 + e) * (TSTEP*64);
    const int o0 = 12*g;           // 12 contiguous complex feats
    const int o1 = 48 + 4*g;       // 4 contiguous real feats

    for (int t = 0; t < TSTEP; ++t) {
        // ---- pack y -> f16 B fragments (state stays f32) ----
        h8 by0, by1;
        #pragma unroll
        for (int i = 0; i < 8; ++i) { by0[i] = (_Float16)yv0[i]; by1[i] = (_Float16)yv1[i]; }

        // ---- layer 1 on matrix pipe: 4 tiles x 2 k-halves ----
        f4 acc1[4];
        #pragma unroll
        for (int q = 0; q < 4; ++q)
            acc1[q] = __builtin_amdgcn_mfma_f32_16x16x32_f16(a1lo[q], by0, b1f[q], 0, 0, 0);
        #pragma unroll
        for (int q = 0; q < 4; ++q)
            acc1[q] = __builtin_amdgcn_mfma_f32_16x16x32_f16(a1hi[q], by1, acc1[q], 0, 0, 0);

        // ---- tanh (16 values) -> f16 B fragments for layer 2 ----
        h8 bu0, bu1;
        #pragma unroll
        for (int j = 0; j < 8; ++j) bu0[j] = (_Float16)fast_tanh(acc1[j>>2][j&3]);
        #pragma unroll
        for (int j = 0; j < 8; ++j) bu1[j] = (_Float16)fast_tanh(acc1[2+(j>>2)][j&3]);

        // ---- layer 2 ----
        f4 acc2[4];
        #pragma unroll
        for (int q = 0; q < 4; ++q)
            acc2[q] = __builtin_amdgcn_mfma_f32_16x16x32_f16(a2lo[q], bu0, b2f[q], 0, 0, 0);
        #pragma unroll
        for (int q = 0; q < 4; ++q)
            acc2[q] = __builtin_amdgcn_mfma_f32_16x16x32_f16(a2hi[q], bu1, acc2[q], 0, 0, 0);

        // ---- pointwise: 6 rotation pairs (coeffs reg-local) + 4 decays (tile 3) ----
        #pragma unroll
        for (int p = 0; p < 6; ++p) {
            const float mu = acc2[p>>1][(2*p)&3];
            const float om = acc2[p>>1][(2*p+1)&3];
            const float E  = texp(DTC * mu);
            const float xx = DTC * om;
            const float q2 = xx * xx;
            float sp = fmaf(q2, 1.0f/120.0f, -1.0f/6.0f); sp = fmaf(q2, sp, 1.0f);
            float cp = fmaf(q2, 1.0f/24.0f,  -0.5f);      cp = fmaf(q2, cp, 1.0f);
            const float s = E * xx * sp;
            const float c = E * cp;
            float y0, y1;
            if (p < 4) { y0 = yv0[2*p];     y1 = yv0[2*p+1]; }
            else       { y0 = yv1[2*(p-4)]; y1 = yv1[2*(p-4)+1]; }
            const float n0 = fmaf(c, y0, -s * y1);
            const float n1 = fmaf(s, y0,  c * y1);
            if (p < 4) { yv0[2*p] = n0;     yv0[2*p+1] = n1; }
            else       { yv1[2*(p-4)] = n0; yv1[2*(p-4)+1] = n1; }
        }
        #pragma unroll
        for (int j = 0; j < 4; ++j) yv1[4+j] *= texp(DTC * acc2[3][j]);

        // ---- async stores straight from registers (no staging, no fences) ----
        f4 s0 = {yv0[0], yv0[1], yv0[2], yv0[3]};
        f4 s1 = {yv0[4], yv0[5], yv0[6], yv0[7]};
        f4 s2 = {yv1[0], yv1[1], yv1[2], yv1[3]};
        f4 s3 = {yv1[4], yv1[5], yv1[6], yv1[7]};
        *reinterpret_cast<f4*>(gp + o0)     = s0;
        *reinterpret_cast<f4*>(gp + o0 + 4) = s1;
        *reinterpret_cast<f4*>(gp + o0 + 8) = s2;
        *reinterpret_cast<f4*>(gp + o1)     = s3;
        gp += 64;
    }
}

extern "C" void kernel_launch(void* const* d_in, const int* in_sizes, int n_in,
                              void* d_out, int out_size, void* d_ws, size_t ws_size,
                              hipStream_t stream) {
    const float* x   = (const float*)d_in[0];
    const float* Wc1 = (const float*)d_in[1];
    const float* bc1 = (const float*)d_in[2];
    const float* Wc2 = (const float*)d_in[3];
    const float* bc2 = (const float*)d_in[4];
    const float* Wr1 = (const float*)d_in[5];
    const float* br1 = (const float*)d_in[6];
    const float* Wr2 = (const float*)d_in[7];
    const float* br2 = (const float*)d_in[8];
    float* out = (float*)d_out;

    koopman_kernel<<<dim3(NB / 16), dim3(64), 0, stream>>>(
        x, Wc1, bc1, Wc2, bc2, Wr1, br1, Wr2, br2, out);
}